// Round 4
// baseline (672.543 us; speedup 1.0000x reference)
//
#include <hip/hip_runtime.h>
#include <math.h>
#include <stdint.h>

#define NLEVELS 16
#define TSIZE   (1u << 19)
#define HMASK   (TSIZE - 1u)
#define P1 2654435761u
#define P2 805459861u

typedef float v2f __attribute__((ext_vector_type(2)));
typedef float v4f __attribute__((ext_vector_type(4)));
typedef uint32_t u32x4 __attribute__((ext_vector_type(4)));

// Per-XCD secondary-stream schedule: up to 4 (level, count, base) segments
// covering the odd-j block slots. Even-j slots are always level 8+xcd.
// HB = first hash ("heavy") level; levels < HB use dense cell tables.
struct LevelParams {
    float    cell[NLEVELS];
    uint32_t res[NLEVELS];
    uint32_t cellOff[NLEVELS];   // cell-index prefix (valid for level < HB)
    uint32_t HB;
    uint32_t slvl[8][4];
    uint32_t scnt[8][4];
    uint32_t sbase[8][4];
};

__device__ __forceinline__ uint32_t bf16_rne(float f) {
    uint32_t b = __float_as_uint(f);
    return (b + 0x7FFFu + ((b >> 16) & 1u)) >> 16;   // round-to-nearest-even
}

// ---------------------------------------------------------------------------
// Phase 0a: f32 tables (levels HB..15) -> packed bf16x2 (4 B/entry) in ws.
__global__ __launch_bounds__(256) void convert_tables_kernel(
    const v2f* __restrict__ tablesOff,   // pre-offset to level HB
    uint32_t* __restrict__ tab16,
    unsigned int nEntries)
{
    unsigned int i = blockIdx.x * 256u + threadIdx.x;
    if (i >= nEntries) return;
    v2f v = __builtin_nontemporal_load(&tablesOff[i]);
    tab16[i] = (bf16_rne(v.x) << 16) | bf16_rne(v.y);
}

// ---------------------------------------------------------------------------
// Phase 0b: build dense cell tables for levels 0..HB-1.
// cells[cellOff[l] + (cx*res+cy)*res+cz] = the 8 bf16-packed corner entries
// (VERTICES order: k -> (x=k>>2, y=(k>>1)&1, z=k&1)), bit-identical to tab16.
// One point-level read is then ONE 32B load (1 L2 line) instead of ~4.25
// random lines. Build is per-cell: 512K cells vs 7.3M point-lookups.
__global__ __launch_bounds__(256) void build_cells_kernel(
    const float2* __restrict__ tables,   // f32 [L][T][2]
    uint32_t* __restrict__ cells,        // [totCells][8]
    LevelParams lp, unsigned int totCells)
{
    unsigned int i = blockIdx.x * 256u + threadIdx.x;
    if (i >= totCells) return;

    unsigned int l = 0;
#pragma unroll
    for (unsigned int k = 1; k < 7u; ++k)
        if (k < lp.HB && i >= lp.cellOff[k]) l = k;

    unsigned int c   = i - lp.cellOff[l];
    unsigned int res = lp.res[l];
    unsigned int cz  = c % res;
    unsigned int t   = c / res;
    unsigned int cy  = t % res;
    unsigned int cx  = t / res;

    const float2* __restrict__ tab = tables + (size_t)l * TSIZE;
    uint32_t u[8];
#pragma unroll
    for (int k = 0; k < 8; ++k) {
        unsigned int vx = cx + (unsigned)(k >> 2);
        unsigned int vy = cy + (unsigned)((k >> 1) & 1);
        unsigned int vz = cz + (unsigned)(k & 1);
        unsigned int h  = (vx ^ (vy * P1) ^ (vz * P2)) & HMASK;
        float2 e = tab[h];
        u[k] = (bf16_rne(e.x) << 16) | bf16_rne(e.y);
    }
    uint32_t* dst = cells + (size_t)i * 8u;
    u32x4 q0; q0.x = u[0]; q0.y = u[1]; q0.z = u[2]; q0.w = u[3];
    u32x4 q1; q1.x = u[4]; q1.y = u[5]; q1.z = u[6]; q1.w = u[7];
    *(u32x4*)dst       = q0;
    *(u32x4*)(dst + 4) = q1;
}

// ---------------------------------------------------------------------------
// Phase 1: compute, level-partitioned across XCDs (blockIdx%8 -> XCD).
// Even j: XCD k runs fine hash level 8+k (table L2-resident on that XCD).
// Odd j: per-XCD secondary stream (l7 hash quarters + cell levels),
// scheduled so per-XCD L2-line work is balanced.
// Rounds 2/3 showed requests and MLP don't matter: the wall is L2 random
// 64B-line service (~10-11 lines/cy/XCD). Cell levels cut lines/pt 4.25->1.
__global__ __launch_bounds__(256) void hashgrid_compute_kernel(
    const float* __restrict__ xyz,
    const uint32_t* __restrict__ tab16,
    const uint32_t* __restrict__ cells,
    v2f* __restrict__ stage,
    LevelParams lp,
    unsigned int npts)
{
    unsigned int b   = blockIdx.x;
    unsigned int xcd = b & 7u;
    unsigned int j   = b >> 3;

    unsigned int level, chunk;
    if (j & 1u) {
        unsigned int t = j >> 1;
        unsigned int s = 0;
        while (s < 3u && t >= lp.scnt[xcd][s]) { t -= lp.scnt[xcd][s]; ++s; }
        level = lp.slvl[xcd][s];
        chunk = lp.sbase[xcd][s] + t;
    } else {
        level = 8u + xcd;
        chunk = j >> 1;
    }
    unsigned int n = chunk * 256u + threadIdx.x;

    float x = xyz[n * 3 + 0];
    float y = xyz[n * 3 + 1];
    float z = xyz[n * 3 + 2];

    float cell = lp.cell[level];   // block-uniform

    // floor(x / cell) with IEEE-correct f32 division (matches reference)
    float fx = floorf(x / cell);
    float fy = floorf(y / cell);
    float fz = floorf(z / cell);

    float mvx = fx * cell, mvy = fy * cell, mvz = fz * cell;
    float dnx = (mvx + cell) - mvx;
    float dny = (mvy + cell) - mvy;
    float dnz = (mvz + cell) - mvz;

    float dx = (x - mvx) * __builtin_amdgcn_rcpf(dnx);
    float dy = (y - mvy) * __builtin_amdgcn_rcpf(dny);
    float dz = (z - mvz) * __builtin_amdgcn_rcpf(dnz);

    unsigned int ix = (unsigned int)(int)fx;
    unsigned int iy = (unsigned int)(int)fy;
    unsigned int iz = (unsigned int)(int)fz;

    uint32_t u0, u1, u2, u3, u4, u5, u6, u7;

    if (level < lp.HB) {
        // Dense cell table: one 32B read (never splits a 64B line).
        // ix,iy,iz < res is guaranteed: for all res used, fl(1/res)*res
        // >= 1-2^-24 >= any f32 x < 1, so floor(x/cell) <= res-1.
        unsigned int res = lp.res[level];
        unsigned int c = (ix * res + iy) * res + iz;
        const u32x4* __restrict__ ct =
            (const u32x4*)cells + 2u * ((size_t)lp.cellOff[level] + c);
        u32x4 q0 = ct[0];
        u32x4 q1 = ct[1];
        u0 = q0.x; u1 = q0.y; u2 = q0.z; u3 = q0.w;
        u4 = q1.x; u5 = q1.y; u6 = q1.z; u7 = q1.w;
    } else {
        unsigned int hx0 = ix,      hx1 = ix + 1u;
        unsigned int hy0 = iy * P1, hy1 = hy0 + P1;
        unsigned int hz0 = iz * P2, hz1 = hz0 + P2;

        const uint32_t* __restrict__ tab =
            tab16 + (size_t)(level - lp.HB) * TSIZE;

        u0 = tab[(hx0 ^ hy0 ^ hz0) & HMASK];
        u1 = tab[(hx0 ^ hy0 ^ hz1) & HMASK];
        u2 = tab[(hx0 ^ hy1 ^ hz0) & HMASK];
        u3 = tab[(hx0 ^ hy1 ^ hz1) & HMASK];
        u4 = tab[(hx1 ^ hy0 ^ hz0) & HMASK];
        u5 = tab[(hx1 ^ hy0 ^ hz1) & HMASK];
        u6 = tab[(hx1 ^ hy1 ^ hz0) & HMASK];
        u7 = tab[(hx1 ^ hy1 ^ hz1) & HMASK];
    }

    #define UX(u) __uint_as_float((u) & 0xFFFF0000u)
    #define UY(u) __uint_as_float((u) << 16)

    float wx0 = 1.0f - dx, wy0 = 1.0f - dy, wz0 = 1.0f - dz;

    float c00x = UX(u0) * wx0 + UX(u4) * dx;
    float c00y = UY(u0) * wx0 + UY(u4) * dx;
    float c01x = UX(u1) * wx0 + UX(u5) * dx;
    float c01y = UY(u1) * wx0 + UY(u5) * dx;
    float c10x = UX(u2) * wx0 + UX(u6) * dx;
    float c10y = UY(u2) * wx0 + UY(u6) * dx;
    float c11x = UX(u3) * wx0 + UX(u7) * dx;
    float c11y = UY(u3) * wx0 + UY(u7) * dx;

    #undef UX
    #undef UY

    float c0x = c00x * wy0 + c10x * dy;
    float c0y = c00y * wy0 + c10y * dy;
    float c1x = c01x * wy0 + c11x * dy;
    float c1y = c01y * wy0 + c11y * dy;

    v2f r;
    r.x = c0x * wz0 + c1x * dz;
    r.y = c0y * wz0 + c1y * dz;

    __builtin_nontemporal_store(r, &stage[(size_t)level * npts + n]);
}

// ---------------------------------------------------------------------------
// Phase 2: transpose stage[l][n] -> out[n][l] via LDS.
__global__ __launch_bounds__(256) void transpose_kernel(
    const v2f* __restrict__ stage, v4f* __restrict__ out4, unsigned int npts)
{
    __shared__ v2f lds[256][17];
    unsigned int tid  = threadIdx.x;
    unsigned int base = blockIdx.x * 256u;

#pragma unroll
    for (int l = 0; l < NLEVELS; ++l)
        lds[tid][l] = __builtin_nontemporal_load(&stage[(size_t)l * npts + base + tid]);

    __syncthreads();

#pragma unroll
    for (int it = 0; it < 8; ++it) {
        unsigned int i = it * 256u + tid;        // 0..2047 within block
        unsigned int p = i >> 3;                 // point within block
        unsigned int k = i & 7u;                 // float4 index within record
        v2f a = lds[p][2 * k];
        v2f c = lds[p][2 * k + 1];
        v4f w; w.x = a.x; w.y = a.y; w.z = c.x; w.w = c.y;
        __builtin_nontemporal_store(w, &out4[(size_t)blockIdx.x * 2048u + i]);
    }
}

// ---------------------------------------------------------------------------
// Fallback: direct f32 gathers, used only if ws is too small.
__global__ __launch_bounds__(256) void hashgrid_direct_kernel(
    const float* __restrict__ xyz,
    const float* __restrict__ tables,
    float2* __restrict__ out,
    LevelParams lp,
    unsigned int total)
{
    unsigned int t = blockIdx.x * 256u + threadIdx.x;
    if (t >= total) return;
    unsigned int n = t >> 4;
    unsigned int l = t & 15u;

    float x = xyz[n * 3 + 0], y = xyz[n * 3 + 1], z = xyz[n * 3 + 2];
    float cell = lp.cell[l];
    float fx = floorf(x / cell), fy = floorf(y / cell), fz = floorf(z / cell);
    float mvx = fx * cell, mvy = fy * cell, mvz = fz * cell;
    float dnx = (mvx + cell) - mvx, dny = (mvy + cell) - mvy, dnz = (mvz + cell) - mvz;
    float dx = (x - mvx) * __builtin_amdgcn_rcpf(dnx);
    float dy = (y - mvy) * __builtin_amdgcn_rcpf(dny);
    float dz = (z - mvz) * __builtin_amdgcn_rcpf(dnz);
    unsigned int ix = (unsigned int)(int)fx, iy = (unsigned int)(int)fy, iz = (unsigned int)(int)fz;
    unsigned int hx0 = ix, hx1 = ix + 1u;
    unsigned int hy0 = iy * P1, hy1 = hy0 + P1;
    unsigned int hz0 = iz * P2, hz1 = hz0 + P2;
    const float2* __restrict__ tab = (const float2*)tables + (size_t)l * TSIZE;
    float2 e0 = tab[(hx0 ^ hy0 ^ hz0) & HMASK];
    float2 e1 = tab[(hx0 ^ hy0 ^ hz1) & HMASK];
    float2 e2 = tab[(hx0 ^ hy1 ^ hz0) & HMASK];
    float2 e3 = tab[(hx0 ^ hy1 ^ hz1) & HMASK];
    float2 e4 = tab[(hx1 ^ hy0 ^ hz0) & HMASK];
    float2 e5 = tab[(hx1 ^ hy0 ^ hz1) & HMASK];
    float2 e6 = tab[(hx1 ^ hy1 ^ hz0) & HMASK];
    float2 e7 = tab[(hx1 ^ hy1 ^ hz1) & HMASK];
    float wx0 = 1.0f - dx, wy0 = 1.0f - dy, wz0 = 1.0f - dz;
    float c00x = e0.x * wx0 + e4.x * dx, c00y = e0.y * wx0 + e4.y * dx;
    float c01x = e1.x * wx0 + e5.x * dx, c01y = e1.y * wx0 + e5.y * dx;
    float c10x = e2.x * wx0 + e6.x * dx, c10y = e2.y * wx0 + e6.y * dx;
    float c11x = e3.x * wx0 + e7.x * dx, c11y = e3.y * wx0 + e7.y * dx;
    float c0x = c00x * wy0 + c10x * dy, c0y = c00y * wy0 + c10y * dy;
    float c1x = c01x * wy0 + c11x * dy, c1y = c01y * wy0 + c11y * dy;
    out[t] = make_float2(c0x * wz0 + c1x * dz, c0y * wz0 + c1y * dz);
}

// ---------------------------------------------------------------------------
extern "C" void kernel_launch(void* const* d_in, const int* in_sizes, int n_in,
                              void* d_out, int out_size, void* d_ws, size_t ws_size,
                              hipStream_t stream)
{
    const float* xyz    = (const float*)d_in[0];
    const float* tables = (const float*)d_in[1];

    // Resolutions via the SAME libm calls CPython makes (bit-exact floors).
    LevelParams lp;
    double bg = exp((log(512.0) - log(16.0)) / 15.0);
    unsigned int resv[NLEVELS];
    for (int i = 0; i < NLEVELS; ++i) {
        int res = (int)floor(16.0 * pow(bg, (double)i));
        resv[i] = (unsigned int)res;
        lp.res[i]  = (unsigned int)res;
        lp.cell[i] = 1.0f / (float)res;
    }

    unsigned int npts = (unsigned int)(in_sizes[0] / 3);
    size_t stageBytes = (size_t)npts * NLEVELS * sizeof(v2f); // 128 MiB

    // Tier selection: HB=7 (cells l0..l6) if ws allows, else HB=6 (fits the
    // 160 MiB budget the previous path used), else direct fallback.
    unsigned int HB = 0;
    size_t tabBytes = 0, cellsCnt = 0;
    for (unsigned int tryHB = 7; tryHB >= 6; --tryHB) {
        size_t cc = 0;
        for (unsigned int l = 0; l < tryHB; ++l)
            cc += (size_t)resv[l] * resv[l] * resv[l];
        size_t tb = (size_t)(NLEVELS - tryHB) * TSIZE * 4u;
        if (ws_size >= tb + cc * 32u + stageBytes && (npts & 255u) == 0u) {
            HB = tryHB; tabBytes = tb; cellsCnt = cc; break;
        }
    }

    if (HB >= 6u) {
        lp.HB = HB;
        size_t off = 0;
        for (unsigned int l = 0; l < NLEVELS; ++l) {
            lp.cellOff[l] = (l < HB) ? (uint32_t)off : 0u;
            if (l < HB) off += (size_t)resv[l] * resv[l] * resv[l];
        }

        uint32_t* tab16 = (uint32_t*)d_ws;
        uint32_t* cells = (uint32_t*)((char*)d_ws + tabBytes);
        v2f* stage = (v2f*)((char*)d_ws + tabBytes + cellsCnt * 32u);

        unsigned int nEntries = (NLEVELS - HB) * TSIZE;
        hipLaunchKernelGGL(convert_tables_kernel,
                           dim3(nEntries / 256u), dim3(256), 0, stream,
                           (const v2f*)tables + (size_t)HB * TSIZE, tab16, nEntries);

        unsigned int totCells = (unsigned int)cellsCnt;
        hipLaunchKernelGGL(build_cells_kernel,
                           dim3((totCells + 255u) / 256u), dim3(256), 0, stream,
                           (const float2*)tables, cells, lp, totCells);

        unsigned int chunks = npts / 256u;                  // 4096 for 2^20 pts

        // Secondary (odd-j) schedule. Totals per XCD must equal `chunks`.
        for (int x = 0; x < 8; ++x)
            for (int s = 0; s < 4; ++s) {
                lp.slvl[x][s] = 0; lp.scnt[x][s] = 0; lp.sbase[x][s] = 0;
            }
        if ((chunks & 3u) == 0u) {
            unsigned int q = chunks / 4u;
            if (HB == 6u) {
                // Heavy: l7 (quarters, XCD0-3), l6 (quarters, XCD4-7).
                for (unsigned x = 0; x < 4; ++x) {
                    lp.slvl[x][0] = 7; lp.scnt[x][0] = q; lp.sbase[x][0] = x * q;
                    lp.slvl[x][1] = x; lp.scnt[x][1] = 3u * q; lp.sbase[x][1] = 0;
                }
                for (unsigned x = 4; x < 8; ++x) {
                    lp.slvl[x][0] = 6; lp.scnt[x][0] = q; lp.sbase[x][0] = (x - 4u) * q;
                }
                lp.slvl[4][1] = 4; lp.scnt[4][1] = 3u * q; lp.sbase[4][1] = 0;
                lp.slvl[5][1] = 5; lp.scnt[5][1] = 3u * q; lp.sbase[5][1] = 0;
                // X6: tails of l4, l0, l1; X7: tails of l5, l2, l3.
                lp.slvl[6][1] = 4; lp.scnt[6][1] = q; lp.sbase[6][1] = 3u * q;
                lp.slvl[6][2] = 0; lp.scnt[6][2] = q; lp.sbase[6][2] = 3u * q;
                lp.slvl[6][3] = 1; lp.scnt[6][3] = q; lp.sbase[6][3] = 3u * q;
                lp.slvl[7][1] = 5; lp.scnt[7][1] = q; lp.sbase[7][1] = 3u * q;
                lp.slvl[7][2] = 2; lp.scnt[7][2] = q; lp.sbase[7][2] = 3u * q;
                lp.slvl[7][3] = 3; lp.scnt[7][3] = q; lp.sbase[7][3] = 3u * q;
            } else { // HB == 7: only l7 is heavy-secondary
                for (unsigned x = 0; x < 4; ++x) {
                    lp.slvl[x][0] = 7; lp.scnt[x][0] = q; lp.sbase[x][0] = x * q;
                    lp.slvl[x][1] = x; lp.scnt[x][1] = 3u * q; lp.sbase[x][1] = 0;
                }
                lp.slvl[4][0] = 4; lp.scnt[4][0] = chunks; lp.sbase[4][0] = 0;
                lp.slvl[5][0] = 5; lp.scnt[5][0] = chunks; lp.sbase[5][0] = 0;
                lp.slvl[6][0] = 6; lp.scnt[6][0] = chunks; lp.sbase[6][0] = 0;
                for (unsigned s = 0; s < 4; ++s) {
                    lp.slvl[7][s] = s; lp.scnt[7][s] = q; lp.sbase[7][s] = 3u * q;
                }
            }
        } else {
            // Generic fallback schedule: xcd -> secondary level xcd (0..7).
            for (int x = 0; x < 8; ++x) {
                lp.slvl[x][0] = (unsigned)x; lp.scnt[x][0] = chunks; lp.sbase[x][0] = 0;
            }
        }

        hipLaunchKernelGGL(hashgrid_compute_kernel,
                           dim3(NLEVELS * chunks), dim3(256), 0, stream,
                           xyz, tab16, cells, stage, lp, npts);

        hipLaunchKernelGGL(transpose_kernel,
                           dim3(npts / 256u), dim3(256), 0, stream,
                           stage, (v4f*)d_out, npts);
    } else {
        unsigned int total = npts * (unsigned int)NLEVELS;
        hipLaunchKernelGGL(hashgrid_direct_kernel,
                           dim3((total + 255u) / 256u), dim3(256), 0, stream,
                           xyz, tables, (float2*)d_out, lp, total);
    }
}